// Round 1
// baseline (275.143 us; speedup 1.0000x reference)
//
#include <hip/hip_runtime.h>
#include <math.h>

#define EPS 1e-8f
#define BS 128
#define W 256
#define N 2048
#define R 4

__device__ inline float wave_sum(float v) {
#pragma unroll
    for (int o = 32; o > 0; o >>= 1) v += __shfl_xor(v, o, 64);
    return v;
}
__device__ inline float wave_max(float v) {
#pragma unroll
    for (int o = 32; o > 0; o >>= 1) v = fmaxf(v, __shfl_xor(v, o, 64));
    return v;
}

// ---------------------------------------------------------------------------
// Kernel 1: per-batch prep. block = 256 (= W), grid = BS.
// Computes: write_m = tanh(m_t), erase_vec = softmax(e_t), MixGate -> g,
// write_key = relu(gated @ oW^T + ob), kn_write = write_key / (||.||+eps),
// kn_read[r] = tanh(k_r)/(||.||+eps).
// ---------------------------------------------------------------------------
__global__ void k_prep(const float* __restrict__ k_r, const float* __restrict__ m_t,
                       const float* __restrict__ e_t, const float* __restrict__ m_er,
                       const float* __restrict__ gW, const float* __restrict__ gb,
                       const float* __restrict__ oW, const float* __restrict__ ob,
                       float* __restrict__ wm_o, float* __restrict__ er_o,
                       float* __restrict__ knw_o, float* __restrict__ knr_o) {
    int b = blockIdx.x, t = threadIdx.x;
    int lane = t & 63, wid = t >> 6;
    __shared__ float red[4];
    __shared__ float gated[2 * W];

    float wm = tanhf(m_t[b * W + t]);
    float me = m_er[b * W + t];
    wm_o[b * W + t] = wm;

    // erase softmax over W
    float e = e_t[b * W + t];
    float mx = wave_max(e);
    if (lane == 0) red[wid] = mx;
    __syncthreads();
    mx = fmaxf(fmaxf(red[0], red[1]), fmaxf(red[2], red[3]));
    __syncthreads();
    float ex = expf(e - mx);
    float s = wave_sum(ex);
    if (lane == 0) red[wid] = s;
    __syncthreads();
    s = red[0] + red[1] + red[2] + red[3];
    __syncthreads();
    er_o[b * W + t] = ex / s;

    // MixGate scalar g
    float p = wm * gW[t] + me * gW[W + t];
    float ps = wave_sum(p);
    if (lane == 0) red[wid] = ps;
    __syncthreads();
    ps = red[0] + red[1] + red[2] + red[3] + gb[0];
    __syncthreads();
    float g = 1.0f / (1.0f + expf(-ps));
    gated[t] = g * wm;
    gated[W + t] = (1.0f - g) * me;
    __syncthreads();

    // write_key[o=t] = relu(sum_j gated[j] * oW[t, j] + ob[t])
    float acc = ob[t];
    const float* orow = oW + (size_t)t * (2 * W);
#pragma unroll 4
    for (int j = 0; j < 2 * W; j++) acc += gated[j] * orow[j];
    float wk = fmaxf(acc, 0.0f);
    float ss = wave_sum(wk * wk);
    if (lane == 0) red[wid] = ss;
    __syncthreads();
    ss = red[0] + red[1] + red[2] + red[3];
    __syncthreads();
    knw_o[b * W + t] = wk / (sqrtf(ss) + EPS);

    // normalized read keys
    for (int r = 0; r < R; r++) {
        float rk = tanhf(k_r[(b * R + r) * W + t]);
        float s2 = wave_sum(rk * rk);
        if (lane == 0) red[wid] = s2;
        __syncthreads();
        s2 = red[0] + red[1] + red[2] + red[3];
        __syncthreads();
        knr_o[(b * R + r) * W + t] = rk / (sqrtf(s2) + EPS);
    }
}

// ---------------------------------------------------------------------------
// Kernel 2: write-direction cosine distances (negated).
// One thread per column n (coalesced over n). grid = (N/256, BS).
// ---------------------------------------------------------------------------
__global__ void k_wdist(const float* __restrict__ mem, const float* __restrict__ knw,
                        float* __restrict__ dist) {
    int b = blockIdx.y;
    int n = blockIdx.x * blockDim.x + threadIdx.x;
    __shared__ float k[W];
    k[threadIdx.x] = knw[b * W + threadIdx.x];
    __syncthreads();
    const float* base = mem + (size_t)b * W * N + n;
    float dot = 0.f, ss = 0.f;
#pragma unroll 4
    for (int w = 0; w < W; w++) {
        float v = base[(size_t)w * N];
        dot += k[w] * v;
        ss += v * v;
    }
    dist[(size_t)b * N + n] = -(dot / (sqrtf(ss) + EPS));
}

// ---------------------------------------------------------------------------
// Kernel 3: in-place row softmax over N=2048 (256 threads, 8 elems/thread).
// grid = number of rows.
// ---------------------------------------------------------------------------
__global__ void k_softmax_rows(float* __restrict__ io) {
    int row = blockIdx.x, t = threadIdx.x;
    int lane = t & 63, wid = t >> 6;
    float* p = io + (size_t)row * N;
    __shared__ float red[4];
    float v[8];
    float mx = -INFINITY;
#pragma unroll
    for (int k = 0; k < 8; k++) {
        v[k] = p[t + k * 256];
        mx = fmaxf(mx, v[k]);
    }
    mx = wave_max(mx);
    if (lane == 0) red[wid] = mx;
    __syncthreads();
    mx = fmaxf(fmaxf(red[0], red[1]), fmaxf(red[2], red[3]));
    __syncthreads();
    float s = 0.f;
#pragma unroll
    for (int k = 0; k < 8; k++) {
        v[k] = expf(v[k] - mx);
        s += v[k];
    }
    s = wave_sum(s);
    if (lane == 0) red[wid] = s;
    __syncthreads();
    s = red[0] + red[1] + red[2] + red[3];
    float inv = 1.0f / s;
#pragma unroll
    for (int k = 0; k < 8; k++) p[t + k * 256] = v[k] * inv;
}

// ---------------------------------------------------------------------------
// Kernel 4: M_new = mem + wwt*(wm - mem*erase), fused with column norm of
// M_new and the 4 read-key dots -> dist_r. One thread per column n.
// ---------------------------------------------------------------------------
__global__ void k_update(const float* __restrict__ mem, const float* __restrict__ wwt,
                         const float* __restrict__ er, const float* __restrict__ wm,
                         const float* __restrict__ knr,
                         float* __restrict__ Mnew, float* __restrict__ dist_r) {
    int b = blockIdx.y;
    int n = blockIdx.x * blockDim.x + threadIdx.x;
    int t = threadIdx.x;
    __shared__ float se[W], sw[W], sk[R * W];
    se[t] = er[b * W + t];
    sw[t] = wm[b * W + t];
#pragma unroll
    for (int j = 0; j < R; j++) sk[j * W + t] = knr[b * R * W + j * W + t];
    __syncthreads();

    float wt = wwt[(size_t)b * N + n];
    const float* mbase = mem + (size_t)b * W * N + n;
    float* obase = Mnew + (size_t)b * W * N + n;
    float ss = 0.f, d0 = 0.f, d1 = 0.f, d2 = 0.f, d3 = 0.f;
    for (int w = 0; w < W; w++) {
        float v = mbase[(size_t)w * N];
        float mn = v + wt * (sw[w] - v * se[w]);
        obase[(size_t)w * N] = mn;
        ss += mn * mn;
        d0 += sk[w] * mn;
        d1 += sk[W + w] * mn;
        d2 += sk[2 * W + w] * mn;
        d3 += sk[3 * W + w] * mn;
    }
    float inv = 1.0f / (sqrtf(ss) + EPS);
    dist_r[((size_t)b * R + 0) * N + n] = d0 * inv;
    dist_r[((size_t)b * R + 1) * N + n] = d1 * inv;
    dist_r[((size_t)b * R + 2) * N + n] = d2 * inv;
    dist_r[((size_t)b * R + 3) * N + n] = d3 * inv;
}

// ---------------------------------------------------------------------------
// Kernel 6: m_read[b,r,w] = sum_n read_wt[b,r,n] * M_new[b,w,n].
// grid = (4 w-tiles of 64, BS). read_wt staged in LDS (32 KB).
// ---------------------------------------------------------------------------
__global__ void k_mread(const float* __restrict__ Mnew, const float* __restrict__ rwt_g,
                        float* __restrict__ m_read) {
    int b = blockIdx.y;
    int w0 = blockIdx.x * 64;
    int t = threadIdx.x;
    int lane = t & 63, wid = t >> 6;
    __shared__ float rwt[R * N];  // 32 KB
    __shared__ float red[16];
#pragma unroll
    for (int k = 0; k < (R * N) / 256; k++)
        rwt[t + k * 256] = rwt_g[(size_t)b * R * N + t + k * 256];
    __syncthreads();

    for (int wi = 0; wi < 64; wi++) {
        int w = w0 + wi;
        const float* row = Mnew + ((size_t)b * W + w) * N;
        float a0 = 0.f, a1 = 0.f, a2 = 0.f, a3 = 0.f;
#pragma unroll
        for (int k = 0; k < 8; k++) {
            int n = t + k * 256;
            float v = row[n];
            a0 += rwt[n] * v;
            a1 += rwt[N + n] * v;
            a2 += rwt[2 * N + n] * v;
            a3 += rwt[3 * N + n] * v;
        }
        a0 = wave_sum(a0);
        a1 = wave_sum(a1);
        a2 = wave_sum(a2);
        a3 = wave_sum(a3);
        if (lane == 0) {
            red[wid * 4 + 0] = a0;
            red[wid * 4 + 1] = a1;
            red[wid * 4 + 2] = a2;
            red[wid * 4 + 3] = a3;
        }
        __syncthreads();
        if (t < R) {
            float sres = red[t] + red[4 + t] + red[8 + t] + red[12 + t];
            m_read[(size_t)b * R * W + t * W + w] = sres;
        }
        __syncthreads();
    }
}

extern "C" void kernel_launch(void* const* d_in, const int* in_sizes, int n_in,
                              void* d_out, int out_size, void* d_ws, size_t ws_size,
                              hipStream_t stream) {
    const float* k_r  = (const float*)d_in[0];
    const float* m_t  = (const float*)d_in[1];
    const float* e_t  = (const float*)d_in[2];
    const float* m_er = (const float*)d_in[3];
    const float* mem  = (const float*)d_in[4];
    const float* gW   = (const float*)d_in[5];
    const float* gb   = (const float*)d_in[6];
    const float* oW   = (const float*)d_in[7];
    const float* ob   = (const float*)d_in[8];

    float* out = (float*)d_out;
    // output layout: m_read (bs,R,W) | M_new (bs,W,N) | read_wt (bs,R,N)
    float* m_read = out;
    float* Mnew   = out + (size_t)BS * R * W;
    float* rwt    = out + (size_t)BS * R * W + (size_t)BS * W * N;

    float* ws  = (float*)d_ws;
    float* wm  = ws;                          // BS*W
    float* er  = ws + (size_t)BS * W;         // BS*W
    float* knw = ws + (size_t)2 * BS * W;     // BS*W
    float* knr = ws + (size_t)3 * BS * W;     // BS*R*W
    float* wdist = ws + (size_t)3 * BS * W + (size_t)BS * R * W;  // BS*N (dist_w, then wwt in-place)

    k_prep<<<BS, 256, 0, stream>>>(k_r, m_t, e_t, m_er, gW, gb, oW, ob, wm, er, knw, knr);
    k_wdist<<<dim3(N / 256, BS), 256, 0, stream>>>(mem, knw, wdist);
    k_softmax_rows<<<BS, 256, 0, stream>>>(wdist);  // -> write_wt in place
    k_update<<<dim3(N / 256, BS), 256, 0, stream>>>(mem, wdist, er, wm, knr, Mnew, rwt);
    k_softmax_rows<<<BS * R, 256, 0, stream>>>(rwt); // dist_r -> read_wt in place
    k_mread<<<dim3(4, BS), 256, 0, stream>>>(Mnew, rwt, m_read);
}

// Round 2
// 259.487 us; speedup vs baseline: 1.0603x; 1.0603x over previous
//
#include <hip/hip_runtime.h>
#include <math.h>

#define EPS 1e-8f
#define BS 128
#define W 256
#define N 2048
#define R 4

__device__ inline float wave_sum(float v) {
#pragma unroll
    for (int o = 32; o > 0; o >>= 1) v += __shfl_xor(v, o, 64);
    return v;
}
__device__ inline float wave_max(float v) {
#pragma unroll
    for (int o = 32; o > 0; o >>= 1) v = fmaxf(v, __shfl_xor(v, o, 64));
    return v;
}

// ---------------------------------------------------------------------------
// Kernel 1: per-batch prep. block = 256 (= W), grid = BS.
// ---------------------------------------------------------------------------
__global__ void k_prep(const float* __restrict__ k_r, const float* __restrict__ m_t,
                       const float* __restrict__ e_t, const float* __restrict__ m_er,
                       const float* __restrict__ gW, const float* __restrict__ gb,
                       const float* __restrict__ oW, const float* __restrict__ ob,
                       float* __restrict__ wm_o, float* __restrict__ er_o,
                       float* __restrict__ knw_o, float* __restrict__ knr_o) {
    int b = blockIdx.x, t = threadIdx.x;
    int lane = t & 63, wid = t >> 6;
    __shared__ float red[4];
    __shared__ float gated[2 * W];

    float wm = tanhf(m_t[b * W + t]);
    float me = m_er[b * W + t];
    wm_o[b * W + t] = wm;

    // erase softmax over W
    float e = e_t[b * W + t];
    float mx = wave_max(e);
    if (lane == 0) red[wid] = mx;
    __syncthreads();
    mx = fmaxf(fmaxf(red[0], red[1]), fmaxf(red[2], red[3]));
    __syncthreads();
    float ex = expf(e - mx);
    float s = wave_sum(ex);
    if (lane == 0) red[wid] = s;
    __syncthreads();
    s = red[0] + red[1] + red[2] + red[3];
    __syncthreads();
    er_o[b * W + t] = ex / s;

    // MixGate scalar g
    float p = wm * gW[t] + me * gW[W + t];
    float ps = wave_sum(p);
    if (lane == 0) red[wid] = ps;
    __syncthreads();
    ps = red[0] + red[1] + red[2] + red[3] + gb[0];
    __syncthreads();
    float g = 1.0f / (1.0f + expf(-ps));
    gated[t] = g * wm;
    gated[W + t] = (1.0f - g) * me;
    __syncthreads();

    // write_key[o=t] = relu(sum_j gated[j] * oW[t, j] + ob[t])
    float acc = ob[t];
    const float* orow = oW + (size_t)t * (2 * W);
#pragma unroll 4
    for (int j = 0; j < 2 * W; j++) acc += gated[j] * orow[j];
    float wk = fmaxf(acc, 0.0f);
    float ss = wave_sum(wk * wk);
    if (lane == 0) red[wid] = ss;
    __syncthreads();
    ss = red[0] + red[1] + red[2] + red[3];
    __syncthreads();
    knw_o[b * W + t] = wk / (sqrtf(ss) + EPS);

    // normalized read keys
    for (int r = 0; r < R; r++) {
        float rk = tanhf(k_r[(b * R + r) * W + t]);
        float s2 = wave_sum(rk * rk);
        if (lane == 0) red[wid] = s2;
        __syncthreads();
        s2 = red[0] + red[1] + red[2] + red[3];
        __syncthreads();
        knr_o[(b * R + r) * W + t] = rk / (sqrtf(s2) + EPS);
    }
}

// ---------------------------------------------------------------------------
// Kernel 2: write-direction cosine distances (negated).
// float2 per thread (coalesced over n). grid = (N/512, BS), block 256.
// ---------------------------------------------------------------------------
__global__ void k_wdist(const float* __restrict__ mem, const float* __restrict__ knw,
                        float* __restrict__ dist) {
    int b = blockIdx.y;
    int t = threadIdx.x;
    int n2 = blockIdx.x * blockDim.x + t;  // float2 index
    __shared__ float k[W];
    k[t] = knw[b * W + t];
    __syncthreads();
    const float2* base = (const float2*)(mem + (size_t)b * W * N) + n2;
    float dx = 0.f, dy = 0.f, sx = 0.f, sy = 0.f;
#pragma unroll 8
    for (int w = 0; w < W; w++) {
        float2 v = base[(size_t)w * (N / 2)];
        float kw = k[w];
        dx += kw * v.x;
        dy += kw * v.y;
        sx += v.x * v.x;
        sy += v.y * v.y;
    }
    float2* dp = (float2*)(dist + (size_t)b * N) + n2;
    *dp = make_float2(-(dx / (sqrtf(sx) + EPS)), -(dy / (sqrtf(sy) + EPS)));
}

// ---------------------------------------------------------------------------
// Kernel 3: in-place row softmax over N=2048 (256 threads, 8 elems/thread).
// ---------------------------------------------------------------------------
__global__ void k_softmax_rows(float* __restrict__ io) {
    int row = blockIdx.x, t = threadIdx.x;
    int lane = t & 63, wid = t >> 6;
    float* p = io + (size_t)row * N;
    __shared__ float red[4];
    float v[8];
    float mx = -INFINITY;
#pragma unroll
    for (int k = 0; k < 8; k++) {
        v[k] = p[t + k * 256];
        mx = fmaxf(mx, v[k]);
    }
    mx = wave_max(mx);
    if (lane == 0) red[wid] = mx;
    __syncthreads();
    mx = fmaxf(fmaxf(red[0], red[1]), fmaxf(red[2], red[3]));
    __syncthreads();
    float s = 0.f;
#pragma unroll
    for (int k = 0; k < 8; k++) {
        v[k] = expf(v[k] - mx);
        s += v[k];
    }
    s = wave_sum(s);
    if (lane == 0) red[wid] = s;
    __syncthreads();
    s = red[0] + red[1] + red[2] + red[3];
    float inv = 1.0f / s;
#pragma unroll
    for (int k = 0; k < 8; k++) p[t + k * 256] = v[k] * inv;
}

// ---------------------------------------------------------------------------
// Kernel 4: M_new = mem + wwt*(wm - mem*erase), fused with column norm of
// M_new and the 4 read-key dots -> dist_r. float2 per thread.
// grid = (N/512, BS), block 256.
// ---------------------------------------------------------------------------
__global__ void k_update(const float* __restrict__ mem, const float* __restrict__ wwt,
                         const float* __restrict__ er, const float* __restrict__ wm,
                         const float* __restrict__ knr,
                         float* __restrict__ Mnew, float* __restrict__ dist_r) {
    int b = blockIdx.y;
    int t = threadIdx.x;
    int n2 = blockIdx.x * blockDim.x + t;  // float2 column index
    __shared__ float se[W], sw[W];
    __shared__ float4 skT[W];  // transposed read keys: skT[w] = {k0,k1,k2,k3}[w]
    se[t] = er[b * W + t];
    sw[t] = wm[b * W + t];
    const float* kb = knr + (size_t)b * R * W;
    skT[t] = make_float4(kb[t], kb[W + t], kb[2 * W + t], kb[3 * W + t]);
    __syncthreads();

    float2 wt = ((const float2*)(wwt + (size_t)b * N))[n2];
    const float2* mb = (const float2*)(mem + (size_t)b * W * N) + n2;
    float2* ob = (float2*)(Mnew + (size_t)b * W * N) + n2;
    float ssx = 0.f, ssy = 0.f;
    float d0x = 0.f, d0y = 0.f, d1x = 0.f, d1y = 0.f;
    float d2x = 0.f, d2y = 0.f, d3x = 0.f, d3y = 0.f;
#pragma unroll 4
    for (int w = 0; w < W; w++) {
        float2 v = mb[(size_t)w * (N / 2)];
        float ew = se[w], mw = sw[w];
        float mnx = v.x + wt.x * (mw - v.x * ew);
        float mny = v.y + wt.y * (mw - v.y * ew);
        ob[(size_t)w * (N / 2)] = make_float2(mnx, mny);
        ssx += mnx * mnx;
        ssy += mny * mny;
        float4 kv = skT[w];
        d0x += kv.x * mnx; d0y += kv.x * mny;
        d1x += kv.y * mnx; d1y += kv.y * mny;
        d2x += kv.z * mnx; d2y += kv.z * mny;
        d3x += kv.w * mnx; d3y += kv.w * mny;
    }
    float ix = 1.0f / (sqrtf(ssx) + EPS);
    float iy = 1.0f / (sqrtf(ssy) + EPS);
    float2* dr = (float2*)(dist_r + (size_t)b * R * N);
    dr[0 * (N / 2) + n2] = make_float2(d0x * ix, d0y * iy);
    dr[1 * (N / 2) + n2] = make_float2(d1x * ix, d1y * iy);
    dr[2 * (N / 2) + n2] = make_float2(d2x * ix, d2y * iy);
    dr[3 * (N / 2) + n2] = make_float2(d3x * ix, d3y * iy);
}

// ---------------------------------------------------------------------------
// Kernel 6: m_read[b,r,w] = sum_n read_wt[b,r,n] * M_new[b,w,n].
// Block = 256 (4 waves) handles (b, 64-row w-tile). Wave wid owns n-chunk
// [wid*512, wid*512+512); its read_wt slice lives in 32 VGPRs (w-invariant).
// Per row: 2 float4 global loads, 32 FMA, wave shuffle-reduce, 1 LDS write.
// One __syncthreads total; tiny cross-wave combine at the end.
// ---------------------------------------------------------------------------
__global__ void k_mread(const float* __restrict__ Mnew, const float* __restrict__ rwt_g,
                        float* __restrict__ m_read) {
    int b = blockIdx.y;
    int w0 = blockIdx.x * 64;
    int t = threadIdx.x;
    int lane = t & 63, wid = t >> 6;
    int nbase = wid * 512 + lane * 8;  // this lane's 8 n-slots

    float4 rw[R][2];
#pragma unroll
    for (int r = 0; r < R; r++) {
        const float4* p = (const float4*)(rwt_g + ((size_t)b * R + r) * N + nbase);
        rw[r][0] = p[0];
        rw[r][1] = p[1];
    }

    __shared__ float part[64 * 16];  // [w_local][wid*4 + r]
    const float* Mb = Mnew + (size_t)b * W * N;
#pragma unroll 2
    for (int wi = 0; wi < 64; wi++) {
        const float4* row = (const float4*)(Mb + (size_t)(w0 + wi) * N + nbase);
        float4 v0 = row[0];
        float4 v1 = row[1];
        float a0 = rw[0][0].x * v0.x + rw[0][0].y * v0.y + rw[0][0].z * v0.z + rw[0][0].w * v0.w
                 + rw[0][1].x * v1.x + rw[0][1].y * v1.y + rw[0][1].z * v1.z + rw[0][1].w * v1.w;
        float a1 = rw[1][0].x * v0.x + rw[1][0].y * v0.y + rw[1][0].z * v0.z + rw[1][0].w * v0.w
                 + rw[1][1].x * v1.x + rw[1][1].y * v1.y + rw[1][1].z * v1.z + rw[1][1].w * v1.w;
        float a2 = rw[2][0].x * v0.x + rw[2][0].y * v0.y + rw[2][0].z * v0.z + rw[2][0].w * v0.w
                 + rw[2][1].x * v1.x + rw[2][1].y * v1.y + rw[2][1].z * v1.z + rw[2][1].w * v1.w;
        float a3 = rw[3][0].x * v0.x + rw[3][0].y * v0.y + rw[3][0].z * v0.z + rw[3][0].w * v0.w
                 + rw[3][1].x * v1.x + rw[3][1].y * v1.y + rw[3][1].z * v1.z + rw[3][1].w * v1.w;
        a0 = wave_sum(a0);
        a1 = wave_sum(a1);
        a2 = wave_sum(a2);
        a3 = wave_sum(a3);
        if (lane == 0) {
            part[wi * 16 + wid * 4 + 0] = a0;
            part[wi * 16 + wid * 4 + 1] = a1;
            part[wi * 16 + wid * 4 + 2] = a2;
            part[wi * 16 + wid * 4 + 3] = a3;
        }
    }
    __syncthreads();
    // 256 threads = 64 w_local x 4 r
    int w = t >> 2, r = t & 3;
    float s = part[w * 16 + 0 + r] + part[w * 16 + 4 + r] +
              part[w * 16 + 8 + r] + part[w * 16 + 12 + r];
    m_read[((size_t)b * R + r) * W + w0 + w] = s;
}

extern "C" void kernel_launch(void* const* d_in, const int* in_sizes, int n_in,
                              void* d_out, int out_size, void* d_ws, size_t ws_size,
                              hipStream_t stream) {
    const float* k_r  = (const float*)d_in[0];
    const float* m_t  = (const float*)d_in[1];
    const float* e_t  = (const float*)d_in[2];
    const float* m_er = (const float*)d_in[3];
    const float* mem  = (const float*)d_in[4];
    const float* gW   = (const float*)d_in[5];
    const float* gb   = (const float*)d_in[6];
    const float* oW   = (const float*)d_in[7];
    const float* ob   = (const float*)d_in[8];

    float* out = (float*)d_out;
    // output layout: m_read (bs,R,W) | M_new (bs,W,N) | read_wt (bs,R,N)
    float* m_read = out;
    float* Mnew   = out + (size_t)BS * R * W;
    float* rwt    = out + (size_t)BS * R * W + (size_t)BS * W * N;

    float* ws  = (float*)d_ws;
    float* wm  = ws;                          // BS*W
    float* er  = ws + (size_t)BS * W;         // BS*W
    float* knw = ws + (size_t)2 * BS * W;     // BS*W
    float* knr = ws + (size_t)3 * BS * W;     // BS*R*W
    float* wdist = ws + (size_t)3 * BS * W + (size_t)BS * R * W;  // BS*N

    k_prep<<<BS, 256, 0, stream>>>(k_r, m_t, e_t, m_er, gW, gb, oW, ob, wm, er, knw, knr);
    k_wdist<<<dim3(N / 512, BS), 256, 0, stream>>>(mem, knw, wdist);
    k_softmax_rows<<<BS, 256, 0, stream>>>(wdist);  // -> write_wt in place
    k_update<<<dim3(N / 512, BS), 256, 0, stream>>>(mem, wdist, er, wm, knr, Mnew, rwt);
    k_softmax_rows<<<BS * R, 256, 0, stream>>>(rwt); // dist_r -> read_wt in place
    k_mread<<<dim3(4, BS), 256, 0, stream>>>(Mnew, rwt, m_read);
}

// Round 3
// 259.176 us; speedup vs baseline: 1.0616x; 1.0012x over previous
//
#include <hip/hip_runtime.h>
#include <math.h>

#define EPS 1e-8f
#define BS 128
#define W 256
#define N 2048
#define R 4

__device__ inline float wave_sum(float v) {
#pragma unroll
    for (int o = 32; o > 0; o >>= 1) v += __shfl_xor(v, o, 64);
    return v;
}
__device__ inline float wave_max(float v) {
#pragma unroll
    for (int o = 32; o > 0; o >>= 1) v = fmaxf(v, __shfl_xor(v, o, 64));
    return v;
}

// ---------------------------------------------------------------------------
// Kernel 1: per-batch prep. block = 256 (= W), grid = BS.
// write_m = tanh(m_t), erase = softmax(e_t), MixGate g, write_key =
// relu(gated@oW^T+ob) normalized, read keys tanh+normalized.
// oW dot: wave-per-output-row, slot-layout float4 loads (coalesced).
// ---------------------------------------------------------------------------
__global__ void k_prep(const float* __restrict__ k_r, const float* __restrict__ m_t,
                       const float* __restrict__ e_t, const float* __restrict__ m_er,
                       const float* __restrict__ gW, const float* __restrict__ gb,
                       const float* __restrict__ oW, const float* __restrict__ ob,
                       float* __restrict__ wm_o, float* __restrict__ er_o,
                       float* __restrict__ knw_o, float* __restrict__ knr_o) {
    int b = blockIdx.x, t = threadIdx.x;
    int lane = t & 63, wid = t >> 6;
    __shared__ float red[4];
    __shared__ float gated[2 * W];
    __shared__ float wk_s[W];

    float wm = tanhf(m_t[b * W + t]);
    float me = m_er[b * W + t];
    wm_o[b * W + t] = wm;

    // erase softmax over W
    float e = e_t[b * W + t];
    float mx = wave_max(e);
    if (lane == 0) red[wid] = mx;
    __syncthreads();
    mx = fmaxf(fmaxf(red[0], red[1]), fmaxf(red[2], red[3]));
    __syncthreads();
    float ex = expf(e - mx);
    float s = wave_sum(ex);
    if (lane == 0) red[wid] = s;
    __syncthreads();
    s = red[0] + red[1] + red[2] + red[3];
    __syncthreads();
    er_o[b * W + t] = ex / s;

    // MixGate scalar g
    float p = wm * gW[t] + me * gW[W + t];
    float ps = wave_sum(p);
    if (lane == 0) red[wid] = ps;
    __syncthreads();
    ps = red[0] + red[1] + red[2] + red[3] + gb[0];
    __syncthreads();
    float g = 1.0f / (1.0f + expf(-ps));
    gated[t] = g * wm;
    gated[W + t] = (1.0f - g) * me;
    __syncthreads();

    // write_key: wave wid computes rows o = wid*64 + i (coalesced float4)
    const float4* g4 = (const float4*)gated;
    float4 g0 = g4[lane];        // elems lane*4 .. +4
    float4 g1 = g4[64 + lane];   // elems 256 + lane*4
    for (int i = 0; i < 64; i++) {
        int o = wid * 64 + i;
        const float4* orow = (const float4*)(oW + (size_t)o * 2 * W);
        float4 w0 = orow[lane];
        float4 w1 = orow[64 + lane];
        float pp = w0.x * g0.x + w0.y * g0.y + w0.z * g0.z + w0.w * g0.w
                 + w1.x * g1.x + w1.y * g1.y + w1.z * g1.z + w1.w * g1.w;
        pp = wave_sum(pp);
        if (lane == 0) wk_s[o] = fmaxf(pp + ob[o], 0.0f);
    }
    __syncthreads();
    float wk = wk_s[t];
    float ss = wave_sum(wk * wk);
    if (lane == 0) red[wid] = ss;
    __syncthreads();
    ss = red[0] + red[1] + red[2] + red[3];
    __syncthreads();
    knw_o[b * W + t] = wk / (sqrtf(ss) + EPS);

    // normalized read keys
    for (int r = 0; r < R; r++) {
        float rk = tanhf(k_r[(b * R + r) * W + t]);
        float s2 = wave_sum(rk * rk);
        if (lane == 0) red[wid] = s2;
        __syncthreads();
        s2 = red[0] + red[1] + red[2] + red[3];
        __syncthreads();
        knr_o[(b * R + r) * W + t] = rk / (sqrtf(s2) + EPS);
    }
}

// ---------------------------------------------------------------------------
// Kernel 2: write-direction cosine distances (negated), raw (pre-softmax).
// float4 per thread. grid = (2, BS), block 256.
// ---------------------------------------------------------------------------
__global__ void k_wdist(const float* __restrict__ mem, const float* __restrict__ knw,
                        float* __restrict__ dist) {
    int b = blockIdx.y;
    int t = threadIdx.x;
    int n4 = blockIdx.x * 256 + t;  // float4 column index
    __shared__ float k[W];
    k[t] = knw[b * W + t];
    __syncthreads();
    const float4* base = (const float4*)(mem + (size_t)b * W * N) + n4;
    float4 dot = make_float4(0.f, 0.f, 0.f, 0.f);
    float4 ss = make_float4(0.f, 0.f, 0.f, 0.f);
#pragma unroll 8
    for (int w = 0; w < W; w++) {
        float4 v = base[(size_t)w * (N / 4)];
        float kw = k[w];
        dot.x += kw * v.x; dot.y += kw * v.y; dot.z += kw * v.z; dot.w += kw * v.w;
        ss.x += v.x * v.x; ss.y += v.y * v.y; ss.z += v.z * v.z; ss.w += v.w * v.w;
    }
    float4 o;
    o.x = -(dot.x / (sqrtf(ss.x) + EPS));
    o.y = -(dot.y / (sqrtf(ss.y) + EPS));
    o.z = -(dot.z / (sqrtf(ss.z) + EPS));
    o.w = -(dot.w / (sqrtf(ss.w) + EPS));
    ((float4*)(dist + (size_t)b * N))[n4] = o;
}

// ---------------------------------------------------------------------------
// Kernel 3: in-place row softmax over N=2048 (for read_wt rows).
// ---------------------------------------------------------------------------
__global__ void k_softmax_rows(float* __restrict__ io) {
    int row = blockIdx.x, t = threadIdx.x;
    int lane = t & 63, wid = t >> 6;
    float* p = io + (size_t)row * N;
    __shared__ float red[4];
    float v[8];
    float mx = -INFINITY;
#pragma unroll
    for (int k = 0; k < 8; k++) {
        v[k] = p[t + k * 256];
        mx = fmaxf(mx, v[k]);
    }
    mx = wave_max(mx);
    if (lane == 0) red[wid] = mx;
    __syncthreads();
    mx = fmaxf(fmaxf(red[0], red[1]), fmaxf(red[2], red[3]));
    __syncthreads();
    float s = 0.f;
#pragma unroll
    for (int k = 0; k < 8; k++) {
        v[k] = expf(v[k] - mx);
        s += v[k];
    }
    s = wave_sum(s);
    if (lane == 0) red[wid] = s;
    __syncthreads();
    s = red[0] + red[1] + red[2] + red[3];
    float inv = 1.0f / s;
#pragma unroll
    for (int k = 0; k < 8; k++) p[t + k * 256] = v[k] * inv;
}

// ---------------------------------------------------------------------------
// Kernel 4: fused write-softmax + memory update + read-dist.
// Prologue: block redundantly computes softmax(raw dist row) -> wt for its
// own 4 columns. Main: M_new = mem + wt*(wm - mem*erase), column norms,
// 4 read-key dots -> raw dist_r. float4 per thread, grid (2, BS), block 256.
// ---------------------------------------------------------------------------
__global__ void k_update(const float* __restrict__ mem, const float* __restrict__ wdist,
                         const float* __restrict__ er, const float* __restrict__ wm,
                         const float* __restrict__ knr,
                         float* __restrict__ Mnew, float* __restrict__ dist_r) {
    int b = blockIdx.y;
    int t = threadIdx.x;
    int lane = t & 63, wid = t >> 6;
    int n4 = blockIdx.x * 256 + t;  // float4 column index
    __shared__ float se[W], sw[W];
    __shared__ float4 skT[W];
    __shared__ float red[4];
    se[t] = er[b * W + t];
    sw[t] = wm[b * W + t];
    const float* kb = knr + (size_t)b * R * W;
    skT[t] = make_float4(kb[t], kb[W + t], kb[2 * W + t], kb[3 * W + t]);

    // --- block-redundant softmax over the full raw dist row (2048) ---
    const float4* drow4 = (const float4*)(wdist + (size_t)b * N);
    float4 a0 = drow4[t];
    float4 a1 = drow4[256 + t];
    float mx = fmaxf(fmaxf(fmaxf(a0.x, a0.y), fmaxf(a0.z, a0.w)),
                     fmaxf(fmaxf(a1.x, a1.y), fmaxf(a1.z, a1.w)));
    mx = wave_max(mx);
    if (lane == 0) red[wid] = mx;
    __syncthreads();
    mx = fmaxf(fmaxf(red[0], red[1]), fmaxf(red[2], red[3]));
    __syncthreads();
    float sm = expf(a0.x - mx) + expf(a0.y - mx) + expf(a0.z - mx) + expf(a0.w - mx)
             + expf(a1.x - mx) + expf(a1.y - mx) + expf(a1.z - mx) + expf(a1.w - mx);
    sm = wave_sum(sm);
    if (lane == 0) red[wid] = sm;
    __syncthreads();
    sm = red[0] + red[1] + red[2] + red[3];
    float inv = 1.0f / sm;
    float4 dmine = drow4[n4];
    float4 wt;
    wt.x = expf(dmine.x - mx) * inv;
    wt.y = expf(dmine.y - mx) * inv;
    wt.z = expf(dmine.z - mx) * inv;
    wt.w = expf(dmine.w - mx) * inv;

    const float4* mb = (const float4*)(mem + (size_t)b * W * N) + n4;
    float4* ob = (float4*)(Mnew + (size_t)b * W * N) + n4;
    float4 ssv = make_float4(0.f, 0.f, 0.f, 0.f);
    float4 d0 = make_float4(0.f, 0.f, 0.f, 0.f);
    float4 d1 = make_float4(0.f, 0.f, 0.f, 0.f);
    float4 d2 = make_float4(0.f, 0.f, 0.f, 0.f);
    float4 d3 = make_float4(0.f, 0.f, 0.f, 0.f);
#pragma unroll 4
    for (int w = 0; w < W; w++) {
        float4 v = mb[(size_t)w * (N / 4)];
        float ew = se[w], mw = sw[w];
        float4 mn;
        mn.x = v.x + wt.x * (mw - v.x * ew);
        mn.y = v.y + wt.y * (mw - v.y * ew);
        mn.z = v.z + wt.z * (mw - v.z * ew);
        mn.w = v.w + wt.w * (mw - v.w * ew);
        ob[(size_t)w * (N / 4)] = mn;
        ssv.x += mn.x * mn.x; ssv.y += mn.y * mn.y;
        ssv.z += mn.z * mn.z; ssv.w += mn.w * mn.w;
        float4 kv = skT[w];
        d0.x += kv.x * mn.x; d0.y += kv.x * mn.y; d0.z += kv.x * mn.z; d0.w += kv.x * mn.w;
        d1.x += kv.y * mn.x; d1.y += kv.y * mn.y; d1.z += kv.y * mn.z; d1.w += kv.y * mn.w;
        d2.x += kv.z * mn.x; d2.y += kv.z * mn.y; d2.z += kv.z * mn.z; d2.w += kv.z * mn.w;
        d3.x += kv.w * mn.x; d3.y += kv.w * mn.y; d3.z += kv.w * mn.z; d3.w += kv.w * mn.w;
    }
    float4 ivn;
    ivn.x = 1.0f / (sqrtf(ssv.x) + EPS);
    ivn.y = 1.0f / (sqrtf(ssv.y) + EPS);
    ivn.z = 1.0f / (sqrtf(ssv.z) + EPS);
    ivn.w = 1.0f / (sqrtf(ssv.w) + EPS);
    float4* dr = (float4*)(dist_r + (size_t)b * R * N);
    dr[0 * (N / 4) + n4] = make_float4(d0.x * ivn.x, d0.y * ivn.y, d0.z * ivn.z, d0.w * ivn.w);
    dr[1 * (N / 4) + n4] = make_float4(d1.x * ivn.x, d1.y * ivn.y, d1.z * ivn.z, d1.w * ivn.w);
    dr[2 * (N / 4) + n4] = make_float4(d2.x * ivn.x, d2.y * ivn.y, d2.z * ivn.z, d2.w * ivn.w);
    dr[3 * (N / 4) + n4] = make_float4(d3.x * ivn.x, d3.y * ivn.y, d3.z * ivn.z, d3.w * ivn.w);
}

// ---------------------------------------------------------------------------
// Kernel 5: m_read[b,r,w] = sum_n read_wt[b,r,n] * M_new[b,w,n].
// grid (4, BS), block 256 (4 waves). Wave (rowgrp=wid>>1, half=wid&1):
// rows w0+rowgrp*32..+32, n in [half*1024, half*1024+1024).
// Slot layout: lane's floats at half*1024 + k*256 + lane*4, k=0..3 (each
// wave-load = 1 KB contiguous). rwt slice lives in 16 float4 VGPRs.
// ---------------------------------------------------------------------------
__global__ void k_mread(const float* __restrict__ Mnew, const float* __restrict__ rwt_g,
                        float* __restrict__ m_read) {
    int b = blockIdx.y;
    int w0 = blockIdx.x * 64;
    int t = threadIdx.x;
    int lane = t & 63, wid = t >> 6;
    int half = wid & 1, rowgrp = wid >> 1;
    int fbase = half * 256 + lane;  // float4 index base within a row

    float4 rw[R][4];
#pragma unroll
    for (int r = 0; r < R; r++) {
        const float4* rrow = (const float4*)(rwt_g + ((size_t)b * R + r) * N);
#pragma unroll
        for (int k = 0; k < 4; k++) rw[r][k] = rrow[fbase + k * 64];
    }

    __shared__ float part[64][2][4];
    const float* Mb = Mnew + (size_t)b * W * N;
#pragma unroll 2
    for (int wi = 0; wi < 32; wi++) {
        int wl = rowgrp * 32 + wi;
        const float4* mrow = (const float4*)(Mb + (size_t)(w0 + wl) * N);
        float4 v[4];
#pragma unroll
        for (int k = 0; k < 4; k++) v[k] = mrow[fbase + k * 64];
        float a0 = 0.f, a1 = 0.f, a2 = 0.f, a3 = 0.f;
#pragma unroll
        for (int k = 0; k < 4; k++) {
            a0 += rw[0][k].x * v[k].x + rw[0][k].y * v[k].y + rw[0][k].z * v[k].z + rw[0][k].w * v[k].w;
            a1 += rw[1][k].x * v[k].x + rw[1][k].y * v[k].y + rw[1][k].z * v[k].z + rw[1][k].w * v[k].w;
            a2 += rw[2][k].x * v[k].x + rw[2][k].y * v[k].y + rw[2][k].z * v[k].z + rw[2][k].w * v[k].w;
            a3 += rw[3][k].x * v[k].x + rw[3][k].y * v[k].y + rw[3][k].z * v[k].z + rw[3][k].w * v[k].w;
        }
        a0 = wave_sum(a0);
        a1 = wave_sum(a1);
        a2 = wave_sum(a2);
        a3 = wave_sum(a3);
        if (lane == 0) {
            part[wl][half][0] = a0;
            part[wl][half][1] = a1;
            part[wl][half][2] = a2;
            part[wl][half][3] = a3;
        }
    }
    __syncthreads();
    int w = t >> 2, r = t & 3;
    float sres = part[w][0][r] + part[w][1][r];
    m_read[((size_t)b * R + r) * W + w0 + w] = sres;
}

extern "C" void kernel_launch(void* const* d_in, const int* in_sizes, int n_in,
                              void* d_out, int out_size, void* d_ws, size_t ws_size,
                              hipStream_t stream) {
    const float* k_r  = (const float*)d_in[0];
    const float* m_t  = (const float*)d_in[1];
    const float* e_t  = (const float*)d_in[2];
    const float* m_er = (const float*)d_in[3];
    const float* mem  = (const float*)d_in[4];
    const float* gW   = (const float*)d_in[5];
    const float* gb   = (const float*)d_in[6];
    const float* oW   = (const float*)d_in[7];
    const float* ob   = (const float*)d_in[8];

    float* out = (float*)d_out;
    // output layout: m_read (bs,R,W) | M_new (bs,W,N) | read_wt (bs,R,N)
    float* m_read = out;
    float* Mnew   = out + (size_t)BS * R * W;
    float* rwt    = out + (size_t)BS * R * W + (size_t)BS * W * N;

    float* ws  = (float*)d_ws;
    float* wm  = ws;                          // BS*W
    float* er  = ws + (size_t)BS * W;         // BS*W
    float* knw = ws + (size_t)2 * BS * W;     // BS*W
    float* knr = ws + (size_t)3 * BS * W;     // BS*R*W
    float* wdist = ws + (size_t)3 * BS * W + (size_t)BS * R * W;  // BS*N raw dist

    k_prep<<<BS, 256, 0, stream>>>(k_r, m_t, e_t, m_er, gW, gb, oW, ob, wm, er, knw, knr);
    k_wdist<<<dim3(2, BS), 256, 0, stream>>>(mem, knw, wdist);
    k_update<<<dim3(2, BS), 256, 0, stream>>>(mem, wdist, er, wm, knr, Mnew, rwt);
    k_softmax_rows<<<BS * R, 256, 0, stream>>>(rwt);  // raw dist_r -> read_wt
    k_mread<<<dim3(4, BS), 256, 0, stream>>>(Mnew, rwt, m_read);
}